// Round 9
// baseline (143.311 us; speedup 1.0000x reference)
//
#include <hip/hip_runtime.h>
#include <math.h>

#define N 4096

static constexpr float F_EPS     = 0.1f;
static constexpr float F_EPSLOGZ = -0.046470802658470075f; // EPS*LOGZ
static constexpr float F_ATOL    = 1e-4f;
static constexpr float F_RTOL    = 1e-4f;
static constexpr int   NITER     = 200;
static constexpr int   NB        = 256;   // persistent blocks, 1/CU
static constexpr int   BT        = 256;   // 4 waves
static constexpr float K2        = 14.426950408889634f;   // 10*log2(e)
static constexpr float HK2       = 7.213475204444817f;    // 5*log2(e)
static constexpr float C1        = -0.6704311637146724f;  // log2(e)*LOGZ
static constexpr float LN2       = 0.6931471805599453f;
static constexpr unsigned SALT   = 0x40000000u;  // epoch salt: never matches 0xAAAAAAAA poison or 0

typedef unsigned long long u64;

// ---------- wave helpers (deterministic fixed-order) ----------
__device__ __forceinline__ float wsum(float x) {
#pragma unroll
  for (int o = 32; o; o >>= 1) x += __shfl_xor(x, o, 64);
  return x;
}
__device__ __forceinline__ float wmax(float x) {
#pragma unroll
  for (int o = 32; o; o >>= 1) x = fmaxf(x, __shfl_xor(x, o, 64));
  return x;
}

// ---------- relaxed agent-scope (cache-bypassing, coherent) access ----------
__device__ __forceinline__ float aload(const float* p) {
  return __hip_atomic_load(p, __ATOMIC_RELAXED, __HIP_MEMORY_SCOPE_AGENT);
}
__device__ __forceinline__ u64 uload64(const u64* p) {
  return __hip_atomic_load(p, __ATOMIC_RELAXED, __HIP_MEMORY_SCOPE_AGENT);
}
__device__ __forceinline__ void ustore64(u64* p, u64 v) {
  __hip_atomic_store(p, v, __ATOMIC_RELAXED, __HIP_MEMORY_SCOPE_AGENT);
}
__device__ __forceinline__ u64 pack2(float lo, float hi) {
  return ((u64)__float_as_uint(hi) << 32) | (u64)__float_as_uint(lo);
}

// ---------- one-hop all-to-all grid barrier, ping-pong slot arrays ----------
// slots: 2 arrays x 256 slots x 8 u64 stride (64B). Arrival word = {payload|SALT+tgt}.
// Thread t polls slot t (equality). Ping-pong (tgt&1) isolates adjacent barriers
// (max skew = 1 barrier), so equality never misses and payloads are never stale.
// decide=1: all blocks reduce the 256 payloads identically -> uniform err.
__device__ __forceinline__ float gbar(u64* __restrict__ slots01, float* __restrict__ red,
                                      int bid, int tid, int lane, int wib,
                                      unsigned tgt, float payload, int decide) {
  u64* slots = slots01 + ((tgt & 1u) << 11);   // 2048 u64 per array
  asm volatile("s_waitcnt vmcnt(0)" ::: "memory");  // my data stores fabric-visible
  __syncthreads();
  if (tid == 0) ustore64(slots + ((u64)bid << 3), ((u64)__float_as_uint(payload) << 32) | (SALT + tgt));
  u64 w;
  while ((unsigned)(w = uload64(slots + ((u64)tid << 3))) != SALT + tgt)
    __builtin_amdgcn_s_sleep(1);
  if (decide) {
    const float m = wmax(__uint_as_float((unsigned)(w >> 32)));
    if (lane == 0) red[wib] = m;
    __syncthreads();
    const float r = fmaxf(fmaxf(red[0], red[1]), fmaxf(red[2], red[3]));
    __syncthreads();
    return r;
  }
  __syncthreads();   // collective AND: all 256 slots confirmed
  return 0.f;
}

// ---------- the whole problem in one persistent kernel (single dispatch) ----------
__global__ void __launch_bounds__(BT) fused_kernel(
    const float* __restrict__ xw, const float2* __restrict__ xs,
    const float* __restrict__ yw, const float2* __restrict__ ys,
    float* __restrict__ pcol, float* __restrict__ prow, float* __restrict__ psav,
    float* __restrict__ fcg, float* __restrict__ gcg,
    float* __restrict__ out, u64* __restrict__ slots) {
  __shared__ __align__(16) float2 xk[N];   // K2 * x coords (32 KB)
  __shared__ __align__(16) float2 yk[N];   // K2 * y coords (32 KB)
  __shared__ __align__(16) float  P[N];    // per-pass log2-offsets (16 KB)
  __shared__ float ew[4];
  __shared__ float red[4];
  const int tid  = threadIdx.x, bid = blockIdx.x;
  const int lane = tid & 63,    wib = tid >> 6;
  const int c0   = bid * 16 + wib * 4;     // 4 owned rows AND 4 owned cols per wave
  unsigned tgt = 0;

  // ==== init: coords->LDS, ywn, prelude P (u=1 seed) computed locally ====
  float mv = 0.f;
  for (int k = tid; k < N; k += BT) {
    const float2 xp = xs[k];
    const float2 yp = ys[k];
    xk[k] = make_float2(K2 * xp.x, K2 * xp.y);
    yk[k] = make_float2(K2 * yp.x, K2 * yp.y);
    P[k]  = log2f(xw[k]) - HK2 * (xp.x * xp.x + xp.y * xp.y);  // seed: l2xw - 5*log2e*x2
    mv = fmaxf(mv, fabsf(yw[k]));
  }
  mv = wmax(mv);
  if (lane == 0) ew[wib] = mv;
  __syncthreads();
  const float ywn = fmaxf(fmaxf(ew[0], ew[1]), fmaxf(ew[2], ew[3]));  // same in all blocks
  __syncthreads();

  float2 xr[4], yc[4];
  float l2xw[4], l2yw[4], ywc[4];
#pragma unroll
  for (int q = 0; q < 4; ++q) {
    xr[q] = xs[c0 + q];
    yc[q] = ys[c0 + q];
    l2xw[q] = log2f(xw[c0 + q]);
    l2yw[q] = log2f(yw[c0 + q]);
    ywc[q]  = yw[c0 + q];
  }

  // ==== prelude colpass: accPrev = colsum with u=1; write Prow (encodes v1) ====
  float accPrev[4];
  {
    float a[4] = {0.f, 0.f, 0.f, 0.f};
#pragma unroll 8
    for (int t = 0; t < 64; ++t) {
      const int i = (t << 6) + lane;
      const float2 c = xk[i]; const float w = P[i];
#pragma unroll
      for (int q = 0; q < 4; ++q)
        a[q] += exp2f(fmaf(c.x, yc[q].x, fmaf(c.y, yc[q].y, w)));
    }
    float o[4];
#pragma unroll
    for (int q = 0; q < 4; ++q) {
      a[q] = wsum(a[q]);
      accPrev[q] = a[q];
      o[q] = l2yw[q] - log2f(a[q]);
    }
    if (lane == 0) {
      ustore64((u64*)&prow[c0],     pack2(o[0], o[1]));
      ustore64((u64*)&prow[c0 + 2], pack2(o[2], o[3]));
    }
  }
  tgt++; gbar(slots, red, bid, tid, lane, wib, tgt, 0.f, 0);

  // ==== Sinkhorn loop ====
  int converged = 0;
  for (int it = 0; it < NITER && !converged; ++it) {
    // ---- rowpass: consume Prow (v), produce Pcol (u) ----
#pragma unroll
    for (int q = 0; q < 8; ++q) {
      const int idx = (tid << 1) + (q << 9);
      const u64 d = uload64((const u64*)&prow[idx]);
      P[idx]     = __uint_as_float((unsigned)d);
      P[idx + 1] = __uint_as_float((unsigned)(d >> 32));
    }
    __syncthreads();
    if (tid < 8) {   // save consumed v (final v for tails)
      const int ix = (bid << 4) + (tid << 1);
      ustore64((u64*)&psav[ix], pack2(P[ix], P[ix + 1]));
    }
    {
      float a[4] = {0.f, 0.f, 0.f, 0.f};
#pragma unroll 8
      for (int t = 0; t < 64; ++t) {
        const int j = (t << 6) + lane;
        const float2 c = yk[j]; const float w = P[j];
#pragma unroll
        for (int q = 0; q < 4; ++q)
          a[q] += exp2f(fmaf(c.x, xr[q].x, fmaf(c.y, xr[q].y, w)));
      }
      float o[4];
#pragma unroll
      for (int q = 0; q < 4; ++q) {
        a[q] = wsum(a[q]);
        o[q] = l2xw[q] - log2f(a[q]);   // ci cancels exactly
      }
      if (lane == 0) {
        ustore64((u64*)&pcol[c0],     pack2(o[0], o[1]));
        ustore64((u64*)&pcol[c0 + 2], pack2(o[2], o[3]));
      }
    }
    tgt++; gbar(slots, red, bid, tid, lane, wib, tgt, 0.f, 0);

    // ---- colpass: consume Pcol (u), produce Prow (next v) + err payload ----
#pragma unroll
    for (int q = 0; q < 8; ++q) {
      const int idx = (tid << 1) + (q << 9);
      const u64 d = uload64((const u64*)&pcol[idx]);
      P[idx]     = __uint_as_float((unsigned)d);
      P[idx + 1] = __uint_as_float((unsigned)(d >> 32));
    }
    __syncthreads();
    {
      float a[4] = {0.f, 0.f, 0.f, 0.f};
#pragma unroll 8
      for (int t = 0; t < 64; ++t) {
        const int i = (t << 6) + lane;
        const float2 c = xk[i]; const float w = P[i];
#pragma unroll
        for (int q = 0; q < 4; ++q)
          a[q] += exp2f(fmaf(c.x, yc[q].x, fmaf(c.y, yc[q].y, w)));
      }
      float e = 0.f, o[4];
#pragma unroll
      for (int q = 0; q < 4; ++q) {
        a[q] = wsum(a[q]);
        e = fmaxf(e, ywc[q] * fabsf(a[q] / accPrev[q] - 1.0f));  // == |v*(K^T u)-yw|
        accPrev[q] = a[q];
        o[q] = l2yw[q] - log2f(a[q]);
      }
      if (lane == 0) {
        ustore64((u64*)&prow[c0],     pack2(o[0], o[1]));
        ustore64((u64*)&prow[c0 + 2], pack2(o[2], o[3]));
        ew[wib] = e;
      }
    }
    __syncthreads();
    const float blkerr = fmaxf(fmaxf(ew[0], ew[1]), fmaxf(ew[2], ew[3]));
    tgt++;
    const float err = gbar(slots, red, bid, tid, lane, wib, tgt, blkerr, 1);
    converged = (err < F_ATOL) || (err / ywn < F_RTOL);
  }

  // ==== phase F: fc (blocks 0-127) / gc (blocks 128-255), 32 each; a12 partial ====
  float sa12;
  {
    const int half = bid >> 7;
    const int base = (bid & 127) * 32 + wib * 8;
#pragma unroll
    for (int q = 0; q < 8; ++q) {
      const int idx = (tid << 1) + (q << 9);
      u64 d;
      if (half == 0) {
        d = uload64((const u64*)&psav[idx]);
        P[idx]     = __uint_as_float((unsigned)d) + C1;
        P[idx + 1] = __uint_as_float((unsigned)(d >> 32)) + C1;
      } else {
        d = uload64((const u64*)&pcol[idx]);
        P[idx]     = __uint_as_float((unsigned)d);
        P[idx + 1] = __uint_as_float((unsigned)(d >> 32));
      }
    }
    __syncthreads();
    float2 rc[8]; float sq2[8]; float acc[8]; float wq[8];
#pragma unroll
    for (int q = 0; q < 8; ++q) {
      const int r = base + q;
      rc[q] = half ? ys[r] : xs[r];
      sq2[q] = rc[q].x * rc[q].x + rc[q].y * rc[q].y;
      wq[q] = half ? yw[r] : xw[r];
      acc[q] = 0.f;
    }
    if (half == 0) {
#pragma unroll 4
      for (int t = 0; t < 64; ++t) {
        const int j = (t << 6) + lane;
        const float2 c = yk[j]; const float w = P[j];
#pragma unroll
        for (int q = 0; q < 8; ++q)
          acc[q] += exp2f(fmaf(c.x, rc[q].x, fmaf(c.y, rc[q].y, w)));
      }
    } else {
#pragma unroll 4
      for (int t = 0; t < 64; ++t) {
        const int i = (t << 6) + lane;
        const float2 c = xk[i]; const float w = P[i];
#pragma unroll
        for (int q = 0; q < 8; ++q)
          acc[q] += exp2f(fmaf(c.x, rc[q].x, fmaf(c.y, rc[q].y, w)));
      }
    }
#pragma unroll
    for (int q = 0; q < 8; ++q) acc[q] = wsum(acc[q]);
    float vals[8]; float s = 0.f;
#pragma unroll
    for (int q = 0; q < 8; ++q) {
      vals[q] = F_EPS * fmaf(LN2, log2f(acc[q]), -5.f * sq2[q]) - F_EPSLOGZ;
      s += vals[q] * wq[q];
    }
    if (lane == 0) {
      float* dst = half ? gcg : fcg;
#pragma unroll
      for (int q = 0; q < 4; ++q)
        ustore64((u64*)&dst[base + (q << 1)], pack2(vals[q << 1], vals[(q << 1) + 1]));
      red[wib] = s;
    }
    __syncthreads();
    sa12 = (red[0] + red[1]) + (red[2] + red[3]);   // uniform within block
  }
  tgt++; gbar(slots, red, bid, tid, lane, wib, tgt, 0.f, 0);

  // ==== phase P: plan partials; payload = a12 + EPS*part; block 0 finishes ====
  {
#pragma unroll
    for (int q = 0; q < 8; ++q) {
      const int idx = (tid << 1) + (q << 9);
      const u64 d = uload64((const u64*)&gcg[idx]);
      const float g0 = __uint_as_float((unsigned)d);
      const float g1 = __uint_as_float((unsigned)(d >> 32));
      const float2 y0 = ys[idx], y1 = ys[idx + 1];
      P[idx]     = fmaf(-HK2, y0.x * y0.x + y0.y * y0.y, fmaf(-K2, g0, log2f(yw[idx]))) - C1;
      P[idx + 1] = fmaf(-HK2, y1.x * y1.x + y1.y * y1.y, fmaf(-K2, g1, log2f(yw[idx + 1]))) - C1;
    }
    __syncthreads();
    float a[4], wx[4];
#pragma unroll
    for (int q = 0; q < 4; ++q) {
      const int r = c0 + q;
      const float x2r = xr[q].x * xr[q].x + xr[q].y * xr[q].y;
      wx[q] = fmaf(-HK2, x2r, fmaf(-K2, aload(&fcg[r]), l2xw[q]));
      a[q] = 0.f;
    }
#pragma unroll 8
    for (int t = 0; t < 64; ++t) {
      const int j = (t << 6) + lane;
      const float2 c = yk[j]; const float w = P[j];
#pragma unroll
      for (int q = 0; q < 4; ++q)
        a[q] += exp2f(fmaf(c.x, xr[q].x, fmaf(c.y, xr[q].y, w)));
    }
#pragma unroll
    for (int q = 0; q < 4; ++q) a[q] = wsum(a[q]);
    if (lane == 0)
      ew[wib] = ((exp2f(wx[0]) * a[0] + exp2f(wx[1]) * a[1]) +
                 (exp2f(wx[2]) * a[2] + exp2f(wx[3]) * a[3]));
    __syncthreads();
    const float partb = (ew[0] + ew[1]) + (ew[2] + ew[3]);
    const float pay = sa12 + F_EPS * partb;

    // final arrival (no release): non-zero blocks store & exit; block 0 reduces.
    tgt++;
    u64* fsl = slots + ((tgt & 1u) << 11);
    asm volatile("s_waitcnt vmcnt(0)" ::: "memory");
    __syncthreads();
    if (tid == 0) ustore64(fsl + ((u64)bid << 3), ((u64)__float_as_uint(pay) << 32) | (SALT + tgt));
    if (bid != 0) return;
    u64 w2;
    while ((unsigned)(w2 = uload64(fsl + ((u64)tid << 3))) != SALT + tgt)
      __builtin_amdgcn_s_sleep(1);
    P[tid] = __uint_as_float((unsigned)(w2 >> 32));
    __syncthreads();
    for (int s2 = 128; s2; s2 >>= 1) {
      if (tid < s2) P[tid] += P[tid + s2];
      __syncthreads();
    }
    if (tid == 0) out[0] = -P[0];
  }
}

extern "C" void kernel_launch(void* const* d_in, const int* in_sizes, int n_in,
                              void* d_out, int out_size, void* d_ws, size_t ws_size,
                              hipStream_t stream) {
  const float*  xw  = (const float*)d_in[0];
  const float2* xs2 = (const float2*)d_in[1];
  const float*  yw  = (const float*)d_in[2];
  const float2* ys2 = (const float2*)d_in[3];
  float* out = (float*)d_out;

  float* w = (float*)d_ws;
  float *pcol = w,          *prow = w + 4096,  *psav = w + 8192,
        *fcg  = w + 12288,  *gcg  = w + 16384;
  u64* slots = (u64*)(w + 20480);   // 2 x 2048 u64 (ping-pong, 64B slot stride)

  fused_kernel<<<NB, BT, 0, stream>>>(xw, xs2, yw, ys2,
                                      pcol, prow, psav, fcg, gcg, out, slots);
}